// Round 6
// baseline (131.871 us; speedup 1.0000x reference)
//
#include <hip/hip_runtime.h>
#include <math.h>

// MEASUREMENT ROUND: march kernel replicated 3x inside one dispatch (grid x3,
// replicas write identical values - benign) so it exceeds the harness's 41 us
// fill dispatches and shows up in rocprof top-5 WITH counters. March internals
// are exactly the round-3 best config (4 samples/lane, branchless edges).
//
// k1 (seg_starts): starts[r] = first sample index of ray r, starts[N] = M.
// k2 (voxel_march): one wave per ray, 4 samples/lane, 256-sample chunks.
// Math: om = exp(-0.5*softplus(x)) = rsqrt(1+exp(x)); alpha = 1-om.
// out[r] = sum w_i * sigmoid(rgb_i) + alphainv_last (white background).

#define MARCH_REPS 3

__device__ __forceinline__ float sigm(float x) {
    return __builtin_amdgcn_rcpf(1.0f + __expf(-x));
}

__global__ __launch_bounds__(256) void seg_starts_kernel(
    const int* __restrict__ ray_id, int* __restrict__ starts, int M, int N)
{
    const int i4 = (blockIdx.x * 256 + threadIdx.x) * 4;
    if (i4 >= M) return;

    if (i4 + 3 < M) {
        const int4 v = *(const int4*)(ray_id + i4);
        const int prev = (i4 == 0) ? -1 : ray_id[i4 - 1];
        for (int r = prev + 1; r <= v.x; ++r) starts[r] = i4 + 0;
        for (int r = v.x + 1; r <= v.y; ++r) starts[r] = i4 + 1;
        for (int r = v.y + 1; r <= v.z; ++r) starts[r] = i4 + 2;
        for (int r = v.z + 1; r <= v.w; ++r) starts[r] = i4 + 3;
        if (i4 + 4 == M) {
            for (int r = v.w + 1; r <= N; ++r) starts[r] = M;  // tail + sentinel
        }
    } else {
        int prev = (i4 == 0) ? -1 : ray_id[i4 - 1];
        for (int k = 0; k < 4 && i4 + k < M; ++k) {
            const int cur = ray_id[i4 + k];
            for (int r = prev + 1; r <= cur; ++r) starts[r] = i4 + k;
            prev = cur;
            if (i4 + k == M - 1)
                for (int r = cur + 1; r <= N; ++r) starts[r] = M;
        }
    }
}

__global__ __launch_bounds__(256) void voxel_march_kernel(
    const float* __restrict__ density,
    const float* __restrict__ rgb_raw,
    const float* __restrict__ shift,
    const int*   __restrict__ starts,
    float* __restrict__ out,
    int M, int N, int blocks_per_rep)
{
    const int lane = threadIdx.x & 63;
    const int wave = threadIdx.x >> 6;
    // replica-fold: 3 replicas perform identical work & identical writes
    const int inner = blockIdx.x % blocks_per_rep;
    const int ray   = inner * 4 + wave;
    if (ray >= N) return;

    const float sh = shift[0];
    const int begin = starts[ray];
    const int end   = starts[ray + 1];

    float carry = 1.0f;
    float acc0 = 0.0f, acc1 = 0.0f, acc2 = 0.0f;

    for (int base = (begin & ~3); base < end; base += 256) {
        const int b4 = base + 4 * lane;
        const int ba = min(b4, M - 4);           // address-safe clamp

        const float4 dd = *(const float4*)(density + ba);
        const float4* rp = (const float4*)(rgb_raw + 3 * ba);
        const float4 c0 = rp[0], c1 = rp[1], c2 = rp[2];

        const bool v0 = (b4 + 0 >= begin) & (b4 + 0 < end);
        const bool v1 = (b4 + 1 >= begin) & (b4 + 1 < end);
        const bool v2 = (b4 + 2 >= begin) & (b4 + 2 < end);
        const bool v3 = (b4 + 3 >= begin) & (b4 + 3 < end);
        const float d0 = v0 ? dd.x : -1e30f;
        const float d1 = v1 ? dd.y : -1e30f;
        const float d2 = v2 ? dd.z : -1e30f;
        const float d3 = v3 ? dd.w : -1e30f;

        const float om0 = __builtin_amdgcn_rsqf(1.0f + __expf(d0 + sh));
        const float om1 = __builtin_amdgcn_rsqf(1.0f + __expf(d1 + sh));
        const float om2 = __builtin_amdgcn_rsqf(1.0f + __expf(d2 + sh));
        const float om3 = __builtin_amdgcn_rsqf(1.0f + __expf(d3 + sh));
        const float al0 = 1.0f - om0, al1 = 1.0f - om1;
        const float al2 = 1.0f - om2, al3 = 1.0f - om3;

        float p = (om0 * om1) * (om2 * om3);
        #pragma unroll
        for (int off = 1; off < 64; off <<= 1) {
            float q = __shfl_up(p, off, 64);
            if (lane >= off) p *= q;
        }
        float excl = __shfl_up(p, 1, 64);
        if (lane == 0) excl = 1.0f;

        float t = carry * excl;
        const float w0 = al0 * t; t *= om0;
        const float w1 = al1 * t; t *= om1;
        const float w2 = al2 * t; t *= om2;
        const float w3 = al3 * t;

        acc0 += w0 * sigm(c0.x) + w1 * sigm(c0.w) + w2 * sigm(c1.z) + w3 * sigm(c2.y);
        acc1 += w0 * sigm(c0.y) + w1 * sigm(c1.x) + w2 * sigm(c1.w) + w3 * sigm(c2.z);
        acc2 += w0 * sigm(c0.z) + w1 * sigm(c1.y) + w2 * sigm(c2.x) + w3 * sigm(c2.w);

        carry *= __shfl(p, 63, 64);
    }

    #pragma unroll
    for (int off = 32; off > 0; off >>= 1) {
        acc0 += __shfl_down(acc0, off, 64);
        acc1 += __shfl_down(acc1, off, 64);
        acc2 += __shfl_down(acc2, off, 64);
    }

    if (lane == 0) {
        out[3 * ray + 0] = acc0 + carry;   // + alphainv_last
        out[3 * ray + 1] = acc1 + carry;
        out[3 * ray + 2] = acc2 + carry;
    }
}

extern "C" void kernel_launch(void* const* d_in, const int* in_sizes, int n_in,
                              void* d_out, int out_size, void* d_ws, size_t ws_size,
                              hipStream_t stream)
{
    const float* density = (const float*)d_in[0];
    const float* rgb_raw = (const float*)d_in[1];
    const float* shift   = (const float*)d_in[2];
    const int*   ray_id  = (const int*)d_in[3];
    float* out = (float*)d_out;

    const int M = in_sizes[0];
    const int N = out_size / 3;

    int* starts = (int*)d_ws;
    const int t1 = (M + 3) / 4;
    seg_starts_kernel<<<(t1 + 255) / 256, 256, 0, stream>>>(ray_id, starts, M, N);

    const int rays_per_block = 4;
    const int blocks_per_rep = (N + rays_per_block - 1) / rays_per_block;
    voxel_march_kernel<<<blocks_per_rep * MARCH_REPS, 256, 0, stream>>>(
        density, rgb_raw, shift, starts, out, M, N, blocks_per_rep);
}

// Round 7
// 114.319 us; speedup vs baseline: 1.1535x; 1.1535x over previous
//
#include <hip/hip_runtime.h>
#include <math.h>

// k1 (seg_starts): starts[r] = first sample index of ray r, starts[N] = M.
//     int4-vectorized coalesced pass over ray_id.
// k2 (voxel_march): ONE WAVE PER WORKGROUP (block=64), one ray per wave,
//     4 samples/lane, 256-sample chunks. 16384 single-wave workgroups give
//     the CU scheduler 1-wave packing/retire granularity -> better occupancy
//     and tail balance than 4-wave blocks (measured: occ 61%, VALU 59%,
//     march ~13.8us; VALU-issue floor ~8.1us).
// Branchless edges: address-clamped vector loads; invalid samples get
//     density -1e30 -> om=1, alpha=0, weight=0.
// Math: om = exp(-0.5*softplus(x)) = rsqrt(1+exp(x)); alpha = 1-om.
// out[r] = sum w_i * sigmoid(rgb_i) + alphainv_last (white background).

__device__ __forceinline__ float sigm(float x) {
    return __builtin_amdgcn_rcpf(1.0f + __expf(-x));
}

__global__ __launch_bounds__(256) void seg_starts_kernel(
    const int* __restrict__ ray_id, int* __restrict__ starts, int M, int N)
{
    const int i4 = (blockIdx.x * 256 + threadIdx.x) * 4;
    if (i4 >= M) return;

    if (i4 + 3 < M) {
        const int4 v = *(const int4*)(ray_id + i4);
        const int prev = (i4 == 0) ? -1 : ray_id[i4 - 1];
        for (int r = prev + 1; r <= v.x; ++r) starts[r] = i4 + 0;
        for (int r = v.x + 1; r <= v.y; ++r) starts[r] = i4 + 1;
        for (int r = v.y + 1; r <= v.z; ++r) starts[r] = i4 + 2;
        for (int r = v.z + 1; r <= v.w; ++r) starts[r] = i4 + 3;
        if (i4 + 4 == M) {
            for (int r = v.w + 1; r <= N; ++r) starts[r] = M;  // tail + sentinel
        }
    } else {
        int prev = (i4 == 0) ? -1 : ray_id[i4 - 1];
        for (int k = 0; k < 4 && i4 + k < M; ++k) {
            const int cur = ray_id[i4 + k];
            for (int r = prev + 1; r <= cur; ++r) starts[r] = i4 + k;
            prev = cur;
            if (i4 + k == M - 1)
                for (int r = cur + 1; r <= N; ++r) starts[r] = M;
        }
    }
}

__global__ __launch_bounds__(64) void voxel_march_kernel(
    const float* __restrict__ density,
    const float* __restrict__ rgb_raw,
    const float* __restrict__ shift,
    const int*   __restrict__ starts,
    float* __restrict__ out,
    int M, int N)
{
    const int lane = threadIdx.x;          // block == one wave
    const int ray  = blockIdx.x;
    if (ray >= N) return;

    const float sh = shift[0];
    const int begin = starts[ray];
    const int end   = starts[ray + 1];

    float carry = 1.0f;
    float acc0 = 0.0f, acc1 = 0.0f, acc2 = 0.0f;

    for (int base = (begin & ~3); base < end; base += 256) {
        const int b4 = base + 4 * lane;
        const int ba = min(b4, M - 4);           // address-safe clamp

        const float4 dd = *(const float4*)(density + ba);
        const float4* rp = (const float4*)(rgb_raw + 3 * ba);
        const float4 c0 = rp[0], c1 = rp[1], c2 = rp[2];

        const bool v0 = (b4 + 0 >= begin) & (b4 + 0 < end);
        const bool v1 = (b4 + 1 >= begin) & (b4 + 1 < end);
        const bool v2 = (b4 + 2 >= begin) & (b4 + 2 < end);
        const bool v3 = (b4 + 3 >= begin) & (b4 + 3 < end);
        const float d0 = v0 ? dd.x : -1e30f;
        const float d1 = v1 ? dd.y : -1e30f;
        const float d2 = v2 ? dd.z : -1e30f;
        const float d3 = v3 ? dd.w : -1e30f;

        const float om0 = __builtin_amdgcn_rsqf(1.0f + __expf(d0 + sh));
        const float om1 = __builtin_amdgcn_rsqf(1.0f + __expf(d1 + sh));
        const float om2 = __builtin_amdgcn_rsqf(1.0f + __expf(d2 + sh));
        const float om3 = __builtin_amdgcn_rsqf(1.0f + __expf(d3 + sh));
        const float al0 = 1.0f - om0, al1 = 1.0f - om1;
        const float al2 = 1.0f - om2, al3 = 1.0f - om3;

        float p = (om0 * om1) * (om2 * om3);
        #pragma unroll
        for (int off = 1; off < 64; off <<= 1) {
            float q = __shfl_up(p, off, 64);
            if (lane >= off) p *= q;
        }
        float excl = __shfl_up(p, 1, 64);
        if (lane == 0) excl = 1.0f;

        float t = carry * excl;
        const float w0 = al0 * t; t *= om0;
        const float w1 = al1 * t; t *= om1;
        const float w2 = al2 * t; t *= om2;
        const float w3 = al3 * t;

        acc0 += w0 * sigm(c0.x) + w1 * sigm(c0.w) + w2 * sigm(c1.z) + w3 * sigm(c2.y);
        acc1 += w0 * sigm(c0.y) + w1 * sigm(c1.x) + w2 * sigm(c1.w) + w3 * sigm(c2.z);
        acc2 += w0 * sigm(c0.z) + w1 * sigm(c1.y) + w2 * sigm(c2.x) + w3 * sigm(c2.w);

        carry *= __shfl(p, 63, 64);
    }

    #pragma unroll
    for (int off = 32; off > 0; off >>= 1) {
        acc0 += __shfl_down(acc0, off, 64);
        acc1 += __shfl_down(acc1, off, 64);
        acc2 += __shfl_down(acc2, off, 64);
    }

    if (lane == 0) {
        out[3 * ray + 0] = acc0 + carry;   // + alphainv_last
        out[3 * ray + 1] = acc1 + carry;
        out[3 * ray + 2] = acc2 + carry;
    }
}

extern "C" void kernel_launch(void* const* d_in, const int* in_sizes, int n_in,
                              void* d_out, int out_size, void* d_ws, size_t ws_size,
                              hipStream_t stream)
{
    const float* density = (const float*)d_in[0];
    const float* rgb_raw = (const float*)d_in[1];
    const float* shift   = (const float*)d_in[2];
    const int*   ray_id  = (const int*)d_in[3];
    float* out = (float*)d_out;

    const int M = in_sizes[0];
    const int N = out_size / 3;

    int* starts = (int*)d_ws;
    const int t1 = (M + 3) / 4;
    seg_starts_kernel<<<(t1 + 255) / 256, 256, 0, stream>>>(ray_id, starts, M, N);

    voxel_march_kernel<<<N, 64, 0, stream>>>(density, rgb_raw, shift,
                                             starts, out, M, N);
}

// Round 8
// 112.573 us; speedup vs baseline: 1.1714x; 1.0155x over previous
//
#include <hip/hip_runtime.h>
#include <math.h>

// k1 (seg_starts): starts[r] = first sample index of ray r, starts[N] = M.
//     int4-vectorized coalesced pass over ray_id.
// k2 (voxel_march): one wave per ray (4 rays / 256-thread block), 4 samples
//     per lane, 256-sample chunks. ALL cross-lane ops are DPP (VALU-speed),
//     not ds_bpermute: wave64 inclusive cumprod = row_shr:1,2,4,8 +
//     row_bcast:15 + row_bcast:31 (6 VALU ops vs 6 dependent DS ops);
//     exclusive shift = wave_shr:1 with old=identity (lane0=1 free);
//     lane-63 broadcast = v_readlane. Epilogue channel sums use the same
//     DPP scan + readlane(63).
// Branchless edges: address-clamped vector loads; invalid samples get
//     density -1e30 -> om=1, alpha=0, weight=0.
// Math: om = exp(-0.5*softplus(x)) = rsqrt(1+exp(x)); alpha = 1-om.
// out[r] = sum w_i * sigmoid(rgb_i) + alphainv_last (white background).

__device__ __forceinline__ float sigm(float x) {
    return __builtin_amdgcn_rcpf(1.0f + __expf(-x));
}

// DPP helpers: old = identity so shifted-in / masked-off rows contribute
// the identity element (bound_ctrl=false keeps `old` for invalid lanes).
template <int Ctrl, int RowMask>
__device__ __forceinline__ float dpp_mul(float x) {
    const int s = __builtin_amdgcn_update_dpp(
        __float_as_int(1.0f), __float_as_int(x), Ctrl, RowMask, 0xf, false);
    return x * __int_as_float(s);
}
template <int Ctrl, int RowMask>
__device__ __forceinline__ float dpp_add(float x) {
    const int s = __builtin_amdgcn_update_dpp(
        __float_as_int(0.0f), __float_as_int(x), Ctrl, RowMask, 0xf, false);
    return x + __int_as_float(s);
}

// wave64 inclusive scans (result on lane i = op over lanes 0..i)
__device__ __forceinline__ float wave_cumprod(float p) {
    p = dpp_mul<0x111, 0xf>(p);   // row_shr:1
    p = dpp_mul<0x112, 0xf>(p);   // row_shr:2
    p = dpp_mul<0x114, 0xf>(p);   // row_shr:4
    p = dpp_mul<0x118, 0xf>(p);   // row_shr:8
    p = dpp_mul<0x142, 0xa>(p);   // row_bcast:15 -> rows 1,3
    p = dpp_mul<0x143, 0xc>(p);   // row_bcast:31 -> rows 2,3
    return p;
}
__device__ __forceinline__ float wave_cumsum(float a) {
    a = dpp_add<0x111, 0xf>(a);
    a = dpp_add<0x112, 0xf>(a);
    a = dpp_add<0x114, 0xf>(a);
    a = dpp_add<0x118, 0xf>(a);
    a = dpp_add<0x142, 0xa>(a);
    a = dpp_add<0x143, 0xc>(a);
    return a;
}
__device__ __forceinline__ float lane63(float x) {
    return __int_as_float(__builtin_amdgcn_readlane(__float_as_int(x), 63));
}

__global__ __launch_bounds__(256) void seg_starts_kernel(
    const int* __restrict__ ray_id, int* __restrict__ starts, int M, int N)
{
    const int i4 = (blockIdx.x * 256 + threadIdx.x) * 4;
    if (i4 >= M) return;

    if (i4 + 3 < M) {
        const int4 v = *(const int4*)(ray_id + i4);
        const int prev = (i4 == 0) ? -1 : ray_id[i4 - 1];
        for (int r = prev + 1; r <= v.x; ++r) starts[r] = i4 + 0;
        for (int r = v.x + 1; r <= v.y; ++r) starts[r] = i4 + 1;
        for (int r = v.y + 1; r <= v.z; ++r) starts[r] = i4 + 2;
        for (int r = v.z + 1; r <= v.w; ++r) starts[r] = i4 + 3;
        if (i4 + 4 == M) {
            for (int r = v.w + 1; r <= N; ++r) starts[r] = M;  // tail + sentinel
        }
    } else {
        int prev = (i4 == 0) ? -1 : ray_id[i4 - 1];
        for (int k = 0; k < 4 && i4 + k < M; ++k) {
            const int cur = ray_id[i4 + k];
            for (int r = prev + 1; r <= cur; ++r) starts[r] = i4 + k;
            prev = cur;
            if (i4 + k == M - 1)
                for (int r = cur + 1; r <= N; ++r) starts[r] = M;
        }
    }
}

__global__ __launch_bounds__(256) void voxel_march_kernel(
    const float* __restrict__ density,
    const float* __restrict__ rgb_raw,
    const float* __restrict__ shift,
    const int*   __restrict__ starts,
    float* __restrict__ out,
    int M, int N)
{
    const int lane = threadIdx.x & 63;
    const int wave = threadIdx.x >> 6;
    const int ray  = blockIdx.x * 4 + wave;
    if (ray >= N) return;

    const float sh = shift[0];
    const int begin = starts[ray];
    const int end   = starts[ray + 1];

    float carry = 1.0f;
    float acc0 = 0.0f, acc1 = 0.0f, acc2 = 0.0f;

    for (int base = (begin & ~3); base < end; base += 256) {
        const int b4 = base + 4 * lane;
        const int ba = min(b4, M - 4);           // address-safe clamp

        const float4 dd = *(const float4*)(density + ba);
        const float4* rp = (const float4*)(rgb_raw + 3 * ba);
        const float4 c0 = rp[0], c1 = rp[1], c2 = rp[2];

        const bool v0 = (b4 + 0 >= begin) & (b4 + 0 < end);
        const bool v1 = (b4 + 1 >= begin) & (b4 + 1 < end);
        const bool v2 = (b4 + 2 >= begin) & (b4 + 2 < end);
        const bool v3 = (b4 + 3 >= begin) & (b4 + 3 < end);
        const float d0 = v0 ? dd.x : -1e30f;
        const float d1 = v1 ? dd.y : -1e30f;
        const float d2 = v2 ? dd.z : -1e30f;
        const float d3 = v3 ? dd.w : -1e30f;

        const float om0 = __builtin_amdgcn_rsqf(1.0f + __expf(d0 + sh));
        const float om1 = __builtin_amdgcn_rsqf(1.0f + __expf(d1 + sh));
        const float om2 = __builtin_amdgcn_rsqf(1.0f + __expf(d2 + sh));
        const float om3 = __builtin_amdgcn_rsqf(1.0f + __expf(d3 + sh));
        const float al0 = 1.0f - om0, al1 = 1.0f - om1;
        const float al2 = 1.0f - om2, al3 = 1.0f - om3;

        // wave-wide inclusive cumprod over lane products (pure DPP/VALU)
        const float p = wave_cumprod((om0 * om1) * (om2 * om3));

        // exclusive prefix: wave_shr:1, lane0 gets identity (old=1.0)
        const float excl = __int_as_float(__builtin_amdgcn_update_dpp(
            __float_as_int(1.0f), __float_as_int(p), 0x138, 0xf, 0xf, false));

        float t = carry * excl;
        const float w0 = al0 * t; t *= om0;
        const float w1 = al1 * t; t *= om1;
        const float w2 = al2 * t; t *= om2;
        const float w3 = al3 * t;

        acc0 += w0 * sigm(c0.x) + w1 * sigm(c0.w) + w2 * sigm(c1.z) + w3 * sigm(c2.y);
        acc1 += w0 * sigm(c0.y) + w1 * sigm(c1.x) + w2 * sigm(c1.w) + w3 * sigm(c2.z);
        acc2 += w0 * sigm(c0.z) + w1 * sigm(c1.y) + w2 * sigm(c2.x) + w3 * sigm(c2.w);

        carry *= lane63(p);       // chunk product broadcast (VALU readlane)
    }

    // epilogue: channel totals via DPP scan, total lives on lane 63
    const float tot0 = lane63(wave_cumsum(acc0));
    const float tot1 = lane63(wave_cumsum(acc1));
    const float tot2 = lane63(wave_cumsum(acc2));

    if (lane == 0) {
        out[3 * ray + 0] = tot0 + carry;   // + alphainv_last
        out[3 * ray + 1] = tot1 + carry;
        out[3 * ray + 2] = tot2 + carry;
    }
}

extern "C" void kernel_launch(void* const* d_in, const int* in_sizes, int n_in,
                              void* d_out, int out_size, void* d_ws, size_t ws_size,
                              hipStream_t stream)
{
    const float* density = (const float*)d_in[0];
    const float* rgb_raw = (const float*)d_in[1];
    const float* shift   = (const float*)d_in[2];
    const int*   ray_id  = (const int*)d_in[3];
    float* out = (float*)d_out;

    const int M = in_sizes[0];
    const int N = out_size / 3;

    int* starts = (int*)d_ws;
    const int t1 = (M + 3) / 4;
    seg_starts_kernel<<<(t1 + 255) / 256, 256, 0, stream>>>(ray_id, starts, M, N);

    const int rays_per_block = 4;
    const int blocks = (N + rays_per_block - 1) / rays_per_block;
    voxel_march_kernel<<<blocks, 256, 0, stream>>>(density, rgb_raw, shift,
                                                   starts, out, M, N);
}